// Round 2
// baseline (447.277 us; speedup 1.0000x reference)
//
#include <hip/hip_runtime.h>
#include <hip/hip_bf16.h>

#define NVOX 200000
#define NTAP 27

typedef __bf16 bf16x8 __attribute__((ext_vector_type(8)));
typedef float  f32x4  __attribute__((ext_vector_type(4)));

// ws layout (bytes)
#define H_BYTES     (NVOX * 64 * 2)            // 25,600,000 per bf16 buffer
#define FB_OFF      0                          // bf16 canonical feats
#define H_OFF       (H_BYTES)                  // bf16 intermediate h
#define WSHUF_BYTES (NTAP * 2 * 4 * 64 * 16)   // 221,184 per conv
#define WS1_OFF     (2 * H_BYTES)
#define WS2_OFF     (WS1_OFF + WSHUF_BYTES)
#define ZROW_OFF    (WS2_OFF + WSHUF_BYTES)    // 256 B zero row
#define FLAG_OFF    (ZROW_OFF + 256)           // flags[0]=float-is-bf16, [1]=nbr-is-i64

static __device__ __forceinline__ unsigned short f2bf_bits(float f) {
    __hip_bfloat16 h = __float2bfloat16(f);
    union { __hip_bfloat16 h; unsigned short u; } u; u.h = h; return u.u;
}
static __device__ __forceinline__ float ld_param(const void* p, int c, int isbf) {
    return isbf ? __bfloat162float(((const __hip_bfloat16*)p)[c])
                : ((const float*)p)[c];
}

// -------- detect dtypes + zero the sentinel row
__global__ void detect_kernel(const unsigned int* __restrict__ v1w,
                              const unsigned int* __restrict__ nbrw,
                              int* __restrict__ flags,
                              unsigned int* __restrict__ zrow) {
    if (threadIdx.x == 0) {
        int bf = 1;
        for (int i = 0; i < 32; ++i) {   // v1 in [0.5,1.5]: bf16 codes 0x3F00..0x3FC0
            unsigned w = v1w[i], lo = w & 0xFFFFu, hi = w >> 16;
            if (!(lo >= 0x3F00u && lo <= 0x3FC0u && hi >= 0x3F00u && hi <= 0x3FC0u)) { bf = 0; break; }
        }
        int n64 = 1;
        for (int i = 0; i < 512; ++i)    // int64 nbr: every odd dword is 0
            if (nbrw[2 * i + 1] != 0u) { n64 = 0; break; }
        flags[0] = bf; flags[1] = n64;
    }
    if (threadIdx.x < 64) zrow[threadIdx.x] = 0u;
}

// -------- canonicalize feats -> bf16 (8 elems / thread; 6250 blocks x 256)
__global__ __launch_bounds__(256)
void convert_kernel(const void* __restrict__ feats, const int* __restrict__ flags,
                    bf16x8* __restrict__ fbuf) {
    int isbf = flags[0];
    long t = (long)blockIdx.x * 256 + threadIdx.x;
    if (isbf) {
        fbuf[t] = ((const bf16x8*)feats)[t];
    } else {
        const float4* f = (const float4*)feats;
        float4 a = f[2 * t], b = f[2 * t + 1];
        union { bf16x8 v; unsigned short u[8]; } o;
        o.u[0] = f2bf_bits(a.x); o.u[1] = f2bf_bits(a.y);
        o.u[2] = f2bf_bits(a.z); o.u[3] = f2bf_bits(a.w);
        o.u[4] = f2bf_bits(b.x); o.u[5] = f2bf_bits(b.y);
        o.u[6] = f2bf_bits(b.z); o.u[7] = f2bf_bits(b.w);
        fbuf[t] = o.v;
    }
}

// -------- shuffle W[k][cin][cout] (fp32 or bf16) -> MFMA B-fragment order
__global__ void prep_kernel(const void* __restrict__ W1, const void* __restrict__ W2,
                            uint4* __restrict__ Ws1, uint4* __restrict__ Ws2,
                            const int* __restrict__ flags) {
    int t = blockIdx.x * blockDim.x + threadIdx.x;
    if (t >= 2 * 13824) return;
    int isbf = flags[0];
    const void* W = (t < 13824) ? W1 : W2;
    uint4* Ws     = (t < 13824) ? Ws1 : Ws2;
    int f = (t < 13824) ? t : t - 13824;
    int k  = f / 512;
    int r  = f % 512;
    int kc = r / 256;
    int r2 = r % 256;
    int nc = r2 / 64;
    int l  = r2 % 64;
    int quad = l >> 4, li = l & 15;
    unsigned short tmp[8];
#pragma unroll
    for (int j = 0; j < 8; ++j) {
        int off = k * 4096 + (kc * 32 + quad * 8 + j) * 64 + (nc * 16 + li);
        if (isbf) { tmp[j] = ((const unsigned short*)W)[off]; }
        else      { tmp[j] = f2bf_bits(((const float*)W)[off]); }
    }
    uint4 v;
    v.x = (unsigned)tmp[0] | ((unsigned)tmp[1] << 16);
    v.y = (unsigned)tmp[2] | ((unsigned)tmp[3] << 16);
    v.z = (unsigned)tmp[4] | ((unsigned)tmp[5] << 16);
    v.w = (unsigned)tmp[6] | ((unsigned)tmp[7] << 16);
    Ws[f] = v;
}

// -------- fused sparse-conv + BN (+ residual) + ReLU
// Block: 64 voxels x 64 cout, 4 waves; wave w owns cout[w*16..w*16+15].
// mfma_f32_16x16x32_bf16: A[m=lane&15][k=quad*8+j], B[k=quad*8+j][n=lane&15],
// D: row=(lane>>4)*4+reg, col=lane&15.
__global__ __launch_bounds__(256)
void conv_bn_kernel(const bf16x8* __restrict__ srcV,   // canonical bf16 [NVOX][64]
                    const void* __restrict__ nbr,
                    const bf16x8* __restrict__ Ws,
                    const void* __restrict__ gg, const void* __restrict__ bb,
                    const void* __restrict__ mm, const void* __restrict__ vv,
                    const __hip_bfloat16* __restrict__ resid,  // null for conv1
                    const bf16x8* __restrict__ zrow,
                    const int* __restrict__ flags,
                    void* __restrict__ dst, int final_out) {
    __shared__ int nbrLDS[NTAP * 64];   // [k][m]
    const int tid  = threadIdx.x;
    const int base = blockIdx.x * 64;
    const int isbf = flags[0];
    const int n64  = flags[1];

    {   // stage neighbor indices, transposed into LDS
        for (int i = tid; i < NTAP * 64; i += 256) {
            int mvox = i / NTAP;
            int ktap = i - mvox * NTAP;
            long gi = (long)base * NTAP + i;
            int idx = n64 ? (int)((const long long*)nbr)[gi] : ((const int*)nbr)[gi];
            nbrLDS[ktap * 64 + mvox] = idx;
        }
    }
    __syncthreads();

    const int w = tid >> 6, l = tid & 63;
    const int quad = l >> 4, li = l & 15;

    f32x4 acc[4];
#pragma unroll
    for (int mt = 0; mt < 4; ++mt) acc[mt] = (f32x4){0.f, 0.f, 0.f, 0.f};

    for (int k = 0; k < NTAP; ++k) {
        bf16x8 b0 = Ws[k * 512 + w * 64 + l];
        bf16x8 b1 = Ws[k * 512 + 256 + w * 64 + l];
#pragma unroll
        for (int mt = 0; mt < 4; ++mt) {
            int idx = nbrLDS[k * 64 + mt * 16 + li];
            const bf16x8* rowp = (idx < NVOX) ? (srcV + (long)idx * 8) : zrow;
            bf16x8 a0 = rowp[quad];       // cin 0..31 slice
            bf16x8 a1 = rowp[4 + quad];   // cin 32..63 slice
            acc[mt] = __builtin_amdgcn_mfma_f32_16x16x32_bf16(a0, b0, acc[mt], 0, 0, 0);
            acc[mt] = __builtin_amdgcn_mfma_f32_16x16x32_bf16(a1, b1, acc[mt], 0, 0, 0);
        }
    }

    const int c = w * 16 + li;
    float scale = ld_param(gg, c, isbf) * rsqrtf(ld_param(vv, c, isbf) + 1e-5f);
    float offs  = ld_param(bb, c, isbf) - ld_param(mm, c, isbf) * scale;
    const int store_bf = (!final_out) || isbf;

#pragma unroll
    for (int mt = 0; mt < 4; ++mt) {
#pragma unroll
        for (int r = 0; r < 4; ++r) {
            long row = base + mt * 16 + quad * 4 + r;
            float val = acc[mt][r] * scale + offs;
            if (resid) val += __bfloat162float(resid[row * 64 + c]);
            val = fmaxf(val, 0.f);
            if (store_bf) ((__hip_bfloat16*)dst)[row * 64 + c] = __float2bfloat16(val);
            else          ((float*)dst)[row * 64 + c] = val;
        }
    }
}

extern "C" void kernel_launch(void* const* d_in, const int* in_sizes, int n_in,
                              void* d_out, int out_size, void* d_ws, size_t ws_size,
                              hipStream_t stream) {
    const void* feats = d_in[0];
    const void* nbr   = d_in[1];
    const void* W1    = d_in[2];
    const void* g1    = d_in[3];
    const void* b1    = d_in[4];
    const void* m1    = d_in[5];
    const void* v1    = d_in[6];
    const void* W2    = d_in[7];
    const void* g2    = d_in[8];
    const void* b2    = d_in[9];
    const void* m2    = d_in[10];
    const void* v2    = d_in[11];

    char* ws = (char*)d_ws;
    bf16x8* fbuf = (bf16x8*)(ws + FB_OFF);
    __hip_bfloat16* h = (__hip_bfloat16*)(ws + H_OFF);
    uint4*  Ws1  = (uint4*)(ws + WS1_OFF);
    uint4*  Ws2  = (uint4*)(ws + WS2_OFF);
    bf16x8* zrow = (bf16x8*)(ws + ZROW_OFF);
    int*    flags = (int*)(ws + FLAG_OFF);

    detect_kernel<<<dim3(1), dim3(64), 0, stream>>>(
        (const unsigned int*)v1, (const unsigned int*)nbr, flags, (unsigned int*)zrow);

    convert_kernel<<<dim3(6250), dim3(256), 0, stream>>>(feats, flags, fbuf);

    prep_kernel<<<dim3(108), dim3(256), 0, stream>>>(W1, W2, Ws1, Ws2, flags);

    conv_bn_kernel<<<dim3(NVOX / 64), dim3(256), 0, stream>>>(
        fbuf, nbr, (const bf16x8*)Ws1, g1, b1, m1, v1,
        /*resid=*/nullptr, zrow, flags, h, /*final_out=*/0);

    conv_bn_kernel<<<dim3(NVOX / 64), dim3(256), 0, stream>>>(
        (const bf16x8*)h, nbr, (const bf16x8*)Ws2, g2, b2, m2, v2,
        /*resid=*/(const __hip_bfloat16*)fbuf, zrow, flags, d_out, /*final_out=*/1);
}

// Round 3
// 420.750 us; speedup vs baseline: 1.0630x; 1.0630x over previous
//
#include <hip/hip_runtime.h>
#include <hip/hip_bf16.h>

#define NVOX 200000
#define NTAP 27

typedef __bf16 bf16x8 __attribute__((ext_vector_type(8)));
typedef float  f32x4  __attribute__((ext_vector_type(4)));

// ws layout (bytes)
#define H_BYTES     (NVOX * 64 * 2)            // 25,600,000 per bf16 buffer
#define FB_OFF      0                          // bf16 canonical feats
#define H_OFF       (H_BYTES)                  // bf16 intermediate h
#define WSHUF_BYTES (NTAP * 2 * 4 * 64 * 16)   // 221,184 per conv
#define WS1_OFF     (2 * H_BYTES)
#define WS2_OFF     (WS1_OFF + WSHUF_BYTES)
#define ZROW_OFF    (WS2_OFF + WSHUF_BYTES)    // 256 B zero row
#define FLAG_OFF    (ZROW_OFF + 256)           // flags[0]=float-is-bf16, [1]=nbr-is-i64

static __device__ __forceinline__ unsigned short f2bf_bits(float f) {
    __hip_bfloat16 h = __float2bfloat16(f);
    union { __hip_bfloat16 h; unsigned short u; } u; u.h = h; return u.u;
}
static __device__ __forceinline__ float ld_param(const void* p, int c, int isbf) {
    return isbf ? __bfloat162float(((const __hip_bfloat16*)p)[c])
                : ((const float*)p)[c];
}

// -------- detect dtypes (wave-parallel, no early exit) + zero sentinel row
__global__ void detect_kernel(const unsigned int* __restrict__ v1w,
                              const unsigned int* __restrict__ nbrw,
                              int* __restrict__ flags,
                              unsigned int* __restrict__ zrow) {
    int t = threadIdx.x;   // 64 threads
    int bfok = 1;
    if (t < 32) {          // v1 in [0.5,1.5]: bf16 codes 0x3F00..0x3FC0
        unsigned w = v1w[t], lo = w & 0xFFFFu, hi = w >> 16;
        bfok = (lo >= 0x3F00u && lo <= 0x3FC0u && hi >= 0x3F00u && hi <= 0x3FC0u);
    }
    int n64ok = 1;
#pragma unroll
    for (int i = 0; i < 8; ++i) {  // int64 nbr: every odd dword zero
        if (nbrw[2 * (t * 8 + i) + 1] != 0u) n64ok = 0;
    }
    int bf  = __all(bfok);
    int n64 = __all(n64ok);
    if (t == 0) { flags[0] = bf; flags[1] = n64; }
    zrow[t] = 0u;
}

// -------- canonicalize feats -> bf16
__global__ __launch_bounds__(256)
void convert_kernel(const void* __restrict__ feats, const int* __restrict__ flags,
                    bf16x8* __restrict__ fbuf) {
    int isbf = flags[0];
    long t = (long)blockIdx.x * 256 + threadIdx.x;
    if (isbf) {
        fbuf[t] = ((const bf16x8*)feats)[t];
    } else {
        const float4* f = (const float4*)feats;
        float4 a = f[2 * t], b = f[2 * t + 1];
        union { bf16x8 v; unsigned short u[8]; } o;
        o.u[0] = f2bf_bits(a.x); o.u[1] = f2bf_bits(a.y);
        o.u[2] = f2bf_bits(a.z); o.u[3] = f2bf_bits(a.w);
        o.u[4] = f2bf_bits(b.x); o.u[5] = f2bf_bits(b.y);
        o.u[6] = f2bf_bits(b.z); o.u[7] = f2bf_bits(b.w);
        fbuf[t] = o.v;
    }
}

// -------- shuffle W[k][cin][cout] -> MFMA B-fragment order
__global__ void prep_kernel(const void* __restrict__ W1, const void* __restrict__ W2,
                            uint4* __restrict__ Ws1, uint4* __restrict__ Ws2,
                            const int* __restrict__ flags) {
    int t = blockIdx.x * blockDim.x + threadIdx.x;
    if (t >= 2 * 13824) return;
    int isbf = flags[0];
    const void* W = (t < 13824) ? W1 : W2;
    uint4* Ws     = (t < 13824) ? Ws1 : Ws2;
    int f = (t < 13824) ? t : t - 13824;
    int k  = f / 512;
    int r  = f % 512;
    int kc = r / 256;
    int r2 = r % 256;
    int nc = r2 / 64;
    int l  = r2 % 64;
    int quad = l >> 4, li = l & 15;
    unsigned short tmp[8];
#pragma unroll
    for (int j = 0; j < 8; ++j) {
        int off = k * 4096 + (kc * 32 + quad * 8 + j) * 64 + (nc * 16 + li);
        if (isbf) { tmp[j] = ((const unsigned short*)W)[off]; }
        else      { tmp[j] = f2bf_bits(((const float*)W)[off]); }
    }
    uint4 v;
    v.x = (unsigned)tmp[0] | ((unsigned)tmp[1] << 16);
    v.y = (unsigned)tmp[2] | ((unsigned)tmp[3] << 16);
    v.z = (unsigned)tmp[4] | ((unsigned)tmp[5] << 16);
    v.w = (unsigned)tmp[6] | ((unsigned)tmp[7] << 16);
    Ws[f] = v;
}

// nbr LDS stride in words (padded: 68%32=4 -> staged writes stride 4 banks,
// and 68%4==0 keeps int4 mask-pass reads 16B-aligned)
#define NSTR 68

// A-prefetch of tap kk into (A0,A1,B0,B1) — branchless, batched
#define PREFETCH(kk, A0, A1, B0, B1) do {                                   \
    B0 = Ws[(kk) * 512 + w * 64 + l];                                       \
    B1 = Ws[(kk) * 512 + 256 + w * 64 + l];                                 \
    _Pragma("unroll")                                                       \
    for (int g = 0; g < 4; ++g) {                                           \
        int idx = nbrLDS[(kk) * NSTR + g * 16 + li];                        \
        const bf16x8* rowp = (idx < NVOX) ? (srcV + (long)idx * 8) : zrow;  \
        A0[g] = rowp[quad];                                                 \
        A1[g] = rowp[4 + quad];                                             \
    } } while (0)

// MFMAs of tap kk, skipped per 16-voxel group when no valid neighbor (exact:
// skipped products are all-zero rows). mg[] is wave-uniform (scalar branch).
#define COMPUTE(kk, A0, A1, B0, B1) do {                                    \
    _Pragma("unroll")                                                       \
    for (int g = 0; g < 4; ++g) {                                           \
        if ((mg[g] >> (kk)) & 1) {                                          \
            acc[g] = __builtin_amdgcn_mfma_f32_16x16x32_bf16(A0[g], B0, acc[g], 0, 0, 0); \
            acc[g] = __builtin_amdgcn_mfma_f32_16x16x32_bf16(A1[g], B1, acc[g], 0, 0, 0); \
        } } } while (0)

// -------- fused sparse-conv + BN (+ residual) + ReLU, pipelined K-loop
__global__ __launch_bounds__(256)
void conv_bn_kernel(const bf16x8* __restrict__ srcV,   // canonical bf16 [NVOX][64]
                    const void* __restrict__ nbr,
                    const bf16x8* __restrict__ Ws,
                    const void* __restrict__ gg, const void* __restrict__ bb,
                    const void* __restrict__ mm, const void* __restrict__ vv,
                    const __hip_bfloat16* __restrict__ resid,  // null for conv1
                    const bf16x8* __restrict__ zrow,
                    const int* __restrict__ flags,
                    void* __restrict__ dst, int final_out) {
    __shared__ int nbrLDS[NTAP * NSTR];   // [k][m], padded
    __shared__ int maskLDS[4];
    const int tid  = threadIdx.x;
    const int base = blockIdx.x * 64;
    const int isbf = flags[0];
    const int n64  = flags[1];

    if (tid < 4) maskLDS[tid] = 0;
    __syncthreads();

    {   // stage neighbor indices, transposed into LDS
        for (int i = tid; i < NTAP * 64; i += 256) {
            int mvox = i / NTAP;
            int ktap = i - mvox * NTAP;
            long gi = (long)base * NTAP + i;
            int idx = n64 ? (int)((const long long*)nbr)[gi] : ((const int*)nbr)[gi];
            nbrLDS[ktap * NSTR + mvox] = idx;
        }
    }
    __syncthreads();

    // build per-(tap, 16-voxel-group) validity bitmask
    if (tid < NTAP * 4) {
        int k = tid >> 2, g = tid & 3;
        const int4* p = (const int4*)&nbrLDS[k * NSTR + g * 16];
        int4 a = p[0], b = p[1], c = p[2], d = p[3];
        int mn = min(min(min(a.x, a.y), min(a.z, a.w)),
                     min(min(min(b.x, b.y), min(b.z, b.w)),
                         min(min(min(c.x, c.y), min(c.z, c.w)),
                             min(min(d.x, d.y), min(d.z, d.w)))));
        if (mn < NVOX) atomicOr(&maskLDS[g], 1 << k);
    }
    __syncthreads();

    const int w = tid >> 6, l = tid & 63;
    const int quad = l >> 4, li = l & 15;

    int mg[4];
#pragma unroll
    for (int g = 0; g < 4; ++g) mg[g] = __builtin_amdgcn_readfirstlane(maskLDS[g]);

    f32x4 acc[4];
#pragma unroll
    for (int g = 0; g < 4; ++g) acc[g] = (f32x4){0.f, 0.f, 0.f, 0.f};

    bf16x8 xa0[4], xa1[4], ya0[4], ya1[4];
    bf16x8 xb0, xb1, yb0, yb1;

    PREFETCH(0, xa0, xa1, xb0, xb1);
    for (int k = 0; k < 26; k += 2) {
        PREFETCH(k + 1, ya0, ya1, yb0, yb1);
        COMPUTE(k, xa0, xa1, xb0, xb1);
        PREFETCH(k + 2, xa0, xa1, xb0, xb1);
        COMPUTE(k + 1, ya0, ya1, yb0, yb1);
    }
    COMPUTE(26, xa0, xa1, xb0, xb1);

    // BN(+residual)+ReLU epilogue; each lane owns one output channel.
    const int c = w * 16 + li;
    float scale = ld_param(gg, c, isbf) * rsqrtf(ld_param(vv, c, isbf) + 1e-5f);
    float offs  = ld_param(bb, c, isbf) - ld_param(mm, c, isbf) * scale;
    const int store_bf = (!final_out) || isbf;

#pragma unroll
    for (int g = 0; g < 4; ++g) {
#pragma unroll
        for (int r = 0; r < 4; ++r) {
            long row = base + g * 16 + quad * 4 + r;
            float val = acc[g][r] * scale + offs;
            if (resid) val += __bfloat162float(resid[row * 64 + c]);
            val = fmaxf(val, 0.f);
            if (store_bf) ((__hip_bfloat16*)dst)[row * 64 + c] = __float2bfloat16(val);
            else          ((float*)dst)[row * 64 + c] = val;
        }
    }
}

extern "C" void kernel_launch(void* const* d_in, const int* in_sizes, int n_in,
                              void* d_out, int out_size, void* d_ws, size_t ws_size,
                              hipStream_t stream) {
    const void* feats = d_in[0];
    const void* nbr   = d_in[1];
    const void* W1    = d_in[2];
    const void* g1    = d_in[3];
    const void* b1    = d_in[4];
    const void* m1    = d_in[5];
    const void* v1    = d_in[6];
    const void* W2    = d_in[7];
    const void* g2    = d_in[8];
    const void* b2    = d_in[9];
    const void* m2    = d_in[10];
    const void* v2    = d_in[11];

    char* ws = (char*)d_ws;
    bf16x8* fbuf = (bf16x8*)(ws + FB_OFF);
    __hip_bfloat16* h = (__hip_bfloat16*)(ws + H_OFF);
    uint4*  Ws1  = (uint4*)(ws + WS1_OFF);
    uint4*  Ws2  = (uint4*)(ws + WS2_OFF);
    bf16x8* zrow = (bf16x8*)(ws + ZROW_OFF);
    int*    flags = (int*)(ws + FLAG_OFF);

    detect_kernel<<<dim3(1), dim3(64), 0, stream>>>(
        (const unsigned int*)v1, (const unsigned int*)nbr, flags, (unsigned int*)zrow);

    convert_kernel<<<dim3(6250), dim3(256), 0, stream>>>(feats, flags, fbuf);

    prep_kernel<<<dim3(108), dim3(256), 0, stream>>>(W1, W2, Ws1, Ws2, flags);

    conv_bn_kernel<<<dim3(NVOX / 64), dim3(256), 0, stream>>>(
        fbuf, nbr, (const bf16x8*)Ws1, g1, b1, m1, v1,
        /*resid=*/nullptr, zrow, flags, h, /*final_out=*/0);

    conv_bn_kernel<<<dim3(NVOX / 64), dim3(256), 0, stream>>>(
        (const bf16x8*)h, nbr, (const bf16x8*)Ws2, g2, b2, m2, v2,
        /*resid=*/(const __hip_bfloat16*)fbuf, zrow, flags, d_out, /*final_out=*/1);
}